// Round 7
// baseline (180.186 us; speedup 1.0000x reference)
//
#include <hip/hip_runtime.h>

// B=4, S=4096, D_IN=1024, D_QK=D_V=64
// out = softmax(relu(XWq+bq) @ relu(XWk+bk)^T) @ relu(XWv+bv) * mask

typedef short s16x8 __attribute__((ext_vector_type(8)));   // 8 bf16 (4 VGPRs) MFMA frag
typedef float fx4   __attribute__((ext_vector_type(4)));   // MFMA accum frag
typedef unsigned short u16x4 __attribute__((ext_vector_type(4)));

#define LOG2E 1.4426950408889634f

__device__ __forceinline__ unsigned short f2bf(float x) {   // fp32 -> bf16 RTN
    unsigned int u = __float_as_uint(x);
    u += 0x7FFFu + ((u >> 16) & 1u);
    return (unsigned short)(u >> 16);
}
__device__ __forceinline__ float bf2f(unsigned short b) {
    return __uint_as_float(((unsigned int)b) << 16);
}

// ---------------------------------------------------------------------------
// Kernel 1: split W{q,k,v} [1024][64] fp32 into W^T hi/lo bf16 [3][64][1024].
// LDS tile-transpose: coalesced reads, contiguous 32 B runs along k on store.
// ---------------------------------------------------------------------------
__global__ __launch_bounds__(256) void prep_w_kernel(
    const float* __restrict__ Wq, const float* __restrict__ Wk, const float* __restrict__ Wv,
    unsigned short* __restrict__ wt_hi, unsigned short* __restrict__ wt_lo)
{
    __shared__ __align__(16) unsigned short sh[64][72];   // [c][k_local]
    __shared__ __align__(16) unsigned short sl[64][72];

    const int y  = blockIdx.x;
    const int kt = blockIdx.y;
    const float* W = (y == 0) ? Wq : (y == 1) ? Wk : Wv;
    const int t  = threadIdx.x;

    const int kl = t >> 2;
    const int c0 = (t & 3) * 16;
    const float* src = W + (size_t)(kt * 64 + kl) * 64 + c0;
    #pragma unroll
    for (int j = 0; j < 4; j++) {
        fx4 v = *(const fx4*)(src + j * 4);
        #pragma unroll
        for (int i = 0; i < 4; i++) {
            float x = v[i];
            unsigned short h = f2bf(x);
            unsigned short l = f2bf(x - bf2f(h));
            sh[c0 + j * 4 + i][kl] = h;
            sl[c0 + j * 4 + i][kl] = l;
        }
    }
    __syncthreads();

    const int c  = t >> 2;
    const int k0 = (t & 3) * 16;
    size_t o = (size_t)(y * 64 + c) * 1024 + kt * 64 + k0;
    *(s16x8*)(wt_hi + o)     = *(const s16x8*)&sh[c][k0];
    *(s16x8*)(wt_hi + o + 8) = *(const s16x8*)&sh[c][k0 + 8];
    *(s16x8*)(wt_lo + o)     = *(const s16x8*)&sl[c][k0];
    *(s16x8*)(wt_lo + o + 8) = *(const s16x8*)&sl[c][k0 + 8];
}

// ---------------------------------------------------------------------------
// Kernel 2: projection v3 — barrier-light streaming GEMM.
// X is streamed global->VGPR directly in MFMA A-fragment layout (lane reads
// 32 B contiguous: row = m0+w*16+l15, k = quad*8..+7); per row the 4 quads
// cover 128 B contiguous -> coalesced, L2-served via XCD swizzle (the 3
// y-blocks of an m-tile land on one XCD). X never touches LDS. Only W^T
// (hi/lo bf16) is staged in LDS, in K-chunks of 128 with register prefetch:
// 2 barriers per 2 K-steps, waves otherwise independent (vs 2 barriers per
// K-step + full LDS round-trip of X before). Compensated bf16 MFMA
// (hh+hl+lh ~ fp32). y==0 -> q hi/lo; y==1 -> k bf16; y==2 -> V^T [b][d][s].
// ---------------------------------------------------------------------------
__global__ __launch_bounds__(256, 3) void proj_kernel(
    const float* __restrict__ X,
    const unsigned short* __restrict__ wt_hi, const unsigned short* __restrict__ wt_lo,
    const float* __restrict__ bq, const float* __restrict__ bk, const float* __restrict__ bv,
    unsigned short* __restrict__ q_hi, unsigned short* __restrict__ q_lo,
    unsigned short* __restrict__ k_bf, unsigned short* __restrict__ vt_g)
{
    __shared__ __align__(16) unsigned short wls[2][64][136];  // [hi/lo][col][k0..127 +8pad]

    const int tid  = threadIdx.x;
    const int lane = tid & 63;
    const int w    = tid >> 6;      // 0..3 (16-row strip per wave)
    const int quad = lane >> 4;
    const int l15  = lane & 15;

    // XCD swizzle decode: f = (mt & 7) + 8*(y + 3*(mt >> 3))
    const int f   = blockIdx.x;
    const int xcd = f & 7;
    const int jj  = f >> 3;
    const int y   = jj % 3;         // 0=q 1=k 2=v
    const int m0  = ((jj / 3) * 8 + xcd) * 64;

    const int row = m0 + w * 16 + l15;
    const float* xbase = X + (size_t)row * 1024;

    // W chunk staging indices (64 cols x 128 k per chunk)
    const int wcol = tid >> 2;
    const int wk0  = (tid & 3) * 32;
    const size_t wgb = (size_t)(y * 64 + wcol) * 1024 + wk0;

    // prefetch W chunk 0
    s16x8 wrh[4], wrl[4];
    #pragma unroll
    for (int i = 0; i < 4; i++) {
        wrh[i] = *(const s16x8*)(wt_hi + wgb + i * 8);
        wrl[i] = *(const s16x8*)(wt_lo + wgb + i * 8);
    }
    // prefetch X for kc=0 (A-fragment layout, 2 ks x 32 B)
    fx4 xc[2][2];
    #pragma unroll
    for (int ks = 0; ks < 2; ks++) {
        xc[ks][0] = *(const fx4*)(xbase + ks * 32 + quad * 8);
        xc[ks][1] = *(const fx4*)(xbase + ks * 32 + quad * 8 + 4);
    }

    fx4 acc[4];
    #pragma unroll
    for (int nt = 0; nt < 4; nt++) acc[nt] = (fx4){0.f, 0.f, 0.f, 0.f};

    for (int ch = 0; ch < 8; ch++) {
        if (ch) __syncthreads();          // prev chunk's LDS readers done
        #pragma unroll
        for (int i = 0; i < 4; i++) {
            *(s16x8*)&wls[0][wcol][wk0 + i * 8] = wrh[i];
            *(s16x8*)&wls[1][wcol][wk0 + i * 8] = wrl[i];
        }
        __syncthreads();
        if (ch < 7) {                     // prefetch next W chunk (L2-hit)
            #pragma unroll
            for (int i = 0; i < 4; i++) {
                wrh[i] = *(const s16x8*)(wt_hi + wgb + (ch + 1) * 128 + i * 8);
                wrl[i] = *(const s16x8*)(wt_lo + wgb + (ch + 1) * 128 + i * 8);
            }
        }

        #pragma unroll
        for (int kk = 0; kk < 2; kk++) {
            const int kc = ch * 2 + kk;
            // prefetch next kc's X while computing this one
            fx4 xn[2][2];
            if (kc < 15) {
                #pragma unroll
                for (int ks = 0; ks < 2; ks++) {
                    xn[ks][0] = *(const fx4*)(xbase + (kc + 1) * 64 + ks * 32 + quad * 8);
                    xn[ks][1] = *(const fx4*)(xbase + (kc + 1) * 64 + ks * 32 + quad * 8 + 4);
                }
            }
            // convert X regs -> hi/lo A-fragments
            s16x8 ah[2], al[2];
            #pragma unroll
            for (int ks = 0; ks < 2; ks++) {
                #pragma unroll
                for (int j = 0; j < 2; j++) {
                    fx4 v = xc[ks][j];
                    #pragma unroll
                    for (int i = 0; i < 4; i++) {
                        unsigned short h = f2bf(v[i]);
                        ah[ks][j * 4 + i] = (short)h;
                        al[ks][j * 4 + i] = (short)f2bf(v[i] - bf2f(h));
                    }
                }
            }
            // MFMA against W fragments from LDS
            #pragma unroll
            for (int nt = 0; nt < 4; nt++) {
                #pragma unroll
                for (int ks = 0; ks < 2; ks++) {
                    const int ko = kk * 64 + ks * 32 + quad * 8;
                    s16x8 bh = *(const s16x8*)&wls[0][nt * 16 + l15][ko];
                    s16x8 bl = *(const s16x8*)&wls[1][nt * 16 + l15][ko];
                    acc[nt] = __builtin_amdgcn_mfma_f32_16x16x32_bf16(ah[ks], bh, acc[nt], 0, 0, 0);
                    acc[nt] = __builtin_amdgcn_mfma_f32_16x16x32_bf16(ah[ks], bl, acc[nt], 0, 0, 0);
                    acc[nt] = __builtin_amdgcn_mfma_f32_16x16x32_bf16(al[ks], bh, acc[nt], 0, 0, 0);
                }
            }
            #pragma unroll
            for (int ks = 0; ks < 2; ks++) {
                xc[ks][0] = xn[ks][0];
                xc[ks][1] = xn[ks][1];
            }
        }
    }
    __syncthreads();   // all LDS reads done before vtr alias writes

    // epilogue: bias + relu, write per-matrix
    const float* bias = (y == 0) ? bq : (y == 1) ? bk : bv;
    const int b   = m0 >> 12;
    const int s0b = m0 & 4095;
    unsigned short* vtr = &wls[0][0][0];  // alias: [64 d][72]

    #pragma unroll
    for (int nt = 0; nt < 4; nt++) {
        int col = nt * 16 + l15;
        float bb = bias[col];
        int rloc = w * 16 + quad * 4;   // local row 0..63
        #pragma unroll
        for (int r = 0; r < 4; r++) {
            float v = acc[nt][r] + bb;
            v = fmaxf(v, 0.f);
            size_t grow = (size_t)(m0 + rloc + r);
            if (y == 0) {
                unsigned short h = f2bf(v);
                unsigned short l = f2bf(v - bf2f(h));
                q_hi[grow * 64 + col] = h;
                q_lo[grow * 64 + col] = l;
            } else if (y == 1) {
                k_bf[grow * 64 + col] = f2bf(v);
            } else {
                vtr[col * 72 + rloc + r] = f2bf(v);  // transpose via LDS
            }
        }
    }
    if (y == 2) {
        __syncthreads();
        int rowd = tid >> 2;          // d 0..63
        int off  = (tid & 3) * 16;    // s chunk (16 el = 32 B)
        s16x8 v0 = *(const s16x8*)&vtr[rowd * 72 + off];
        s16x8 v1 = *(const s16x8*)&vtr[rowd * 72 + off + 8];
        *(s16x8*)(vt_g + (size_t)(b * 64 + rowd) * 4096 + s0b + off)     = v0;
        *(s16x8*)(vt_g + (size_t)(b * 64 + rowd) * 4096 + s0b + off + 8) = v1;
    }
}

// ---------------------------------------------------------------------------
// Kernel 3: fused attention, KV-split. grid (64 qtiles, 8 chunks, 4 batch) =
// 2048 blocks. Block = 64 q-rows, 4 waves, 8 KV tiles each. LDS 23.5 KB
// (pt halved: keys processed in two 32-key halves) -> 6 blocks/CU.
// Writes UNNORMALIZED partial O (bf16) and row-sum l (fp32).
// No online max: q,k >= 0 post-relu => exp safe in fp32.
// ---------------------------------------------------------------------------
__global__ __launch_bounds__(256, 6) void attn_kernel(
    const unsigned short* __restrict__ q_hi, const unsigned short* __restrict__ q_lo,
    const unsigned short* __restrict__ k_bf, const unsigned short* __restrict__ vt_g,
    unsigned short* __restrict__ pOb, float* __restrict__ pL)
{
    __shared__ __align__(16) unsigned short kt[64][72];      // [key][dim]
    __shared__ __align__(16) unsigned short vt[64][72];      // [dim][key]  (V^T)
    __shared__ __align__(16) unsigned short pt[4][16][40];   // per-wave P [q][key half]

    const int tid  = threadIdx.x;
    const int lane = tid & 63;
    const int w    = tid >> 6;
    const int quad = lane >> 4;
    const int l15  = lane & 15;
    const int ck   = blockIdx.y;         // key chunk (512 keys)
    const int b    = blockIdx.z;
    const int q0   = blockIdx.x * 64;    // within batch

    // Q fragments (A layout: m=lane&15, k=quad*8+j), split hi/lo
    const size_t qoff = ((size_t)b * 4096 + q0 + w * 16 + l15) * 64 + quad * 8;
    s16x8 qh0 = *(const s16x8*)(q_hi + qoff);
    s16x8 qh1 = *(const s16x8*)(q_hi + qoff + 32);
    s16x8 ql0 = *(const s16x8*)(q_lo + qoff);
    s16x8 ql1 = *(const s16x8*)(q_lo + qoff + 32);

    fx4 accO[4];
    #pragma unroll
    for (int nt = 0; nt < 4; nt++) accO[nt] = (fx4){0.f, 0.f, 0.f, 0.f};
    float lsum[4] = {0.f, 0.f, 0.f, 0.f};

    const unsigned short* kgb = k_bf + (size_t)b * 4096 * 64;  // [s][64]
    const unsigned short* vgb = vt_g + (size_t)b * 64 * 4096;  // [d][s]

    const int srow = tid >> 3;        // 0..31
    const int soff = (tid & 7) * 8;

    for (int it = ck * 8; it < ck * 8 + 8; it++) {
        const unsigned short* kg = kgb + (size_t)it * 4096;    // 64 keys x 64 dims
        #pragma unroll
        for (int i = 0; i < 2; i++) {
            int row = srow + i * 32;
            *(s16x8*)&kt[row][soff] = *(const s16x8*)(kg + (size_t)row * 64 + soff);
            *(s16x8*)&vt[row][soff] = *(const s16x8*)(vgb + (size_t)row * 4096 + it * 64 + soff);
        }
        __syncthreads();

        #pragma unroll
        for (int kh = 0; kh < 2; kh++) {
            // S = Q K^T for 32-key half (hi/lo compensated)
            #pragma unroll
            for (int nt2 = 0; nt2 < 2; nt2++) {
                int key = kh * 32 + nt2 * 16 + l15;
                s16x8 k0 = *(const s16x8*)&kt[key][quad * 8];
                s16x8 k1 = *(const s16x8*)&kt[key][32 + quad * 8];
                fx4 sc = (fx4){0.f, 0.f, 0.f, 0.f};
                sc = __builtin_amdgcn_mfma_f32_16x16x32_bf16(qh0, k0, sc, 0, 0, 0);
                sc = __builtin_amdgcn_mfma_f32_16x16x32_bf16(ql0, k0, sc, 0, 0, 0);
                sc = __builtin_amdgcn_mfma_f32_16x16x32_bf16(qh1, k1, sc, 0, 0, 0);
                sc = __builtin_amdgcn_mfma_f32_16x16x32_bf16(ql1, k1, sc, 0, 0, 0);
                // P = exp(S) -> bf16 -> wave-private LDS (C -> A layout)
                #pragma unroll
                for (int r = 0; r < 4; r++) {
                    float p = __builtin_amdgcn_exp2f(sc[r] * LOG2E);
                    unsigned short pb = f2bf(p);
                    lsum[r] += bf2f(pb);   // denominator matches rounded numerator
                    pt[w][quad * 4 + r][nt2 * 16 + l15] = pb;
                }
            }
            // O += P_half V_half  (k=32 exactly fills one MFMA)
            s16x8 pa = *(const s16x8*)&pt[w][l15][quad * 8];
            #pragma unroll
            for (int nt = 0; nt < 4; nt++) {
                s16x8 vf = *(const s16x8*)&vt[nt * 16 + l15][kh * 32 + quad * 8];
                accO[nt] = __builtin_amdgcn_mfma_f32_16x16x32_bf16(pa, vf, accO[nt], 0, 0, 0);
            }
        }
        __syncthreads();
    }

    // reduce row-sums across the 16 lanes sharing each row group
    #pragma unroll
    for (int r = 0; r < 4; r++) {
        float v = lsum[r];
        #pragma unroll
        for (int o = 1; o < 16; o <<= 1) v += __shfl_xor(v, o);
        lsum[r] = v;
    }
    // write partials: pOb[ck][b*4096+q][64] (bf16), pL[ck][b*4096+q] (fp32)
    #pragma unroll
    for (int r = 0; r < 4; r++) {
        int qrow = q0 + w * 16 + quad * 4 + r;
        size_t grow = (size_t)b * 4096 + qrow;
        #pragma unroll
        for (int nt = 0; nt < 4; nt++)
            pOb[((size_t)ck * 16384 + grow) * 64 + nt * 16 + l15] = f2bf(accO[nt][r]);
        if (l15 == 0)
            pL[(size_t)ck * 16384 + grow] = lsum[r];
    }
}

// ---------------------------------------------------------------------------
// Kernel 4: combine partials: out = (sum_c pOb) * mask / (sum_c pL)
// ---------------------------------------------------------------------------
__global__ __launch_bounds__(256) void combine_kernel(
    const unsigned short* __restrict__ pOb, const float* __restrict__ pL,
    const float* __restrict__ mask, float* __restrict__ out)
{
    int idx = blockIdx.x * 256 + threadIdx.x;   // 262144 = (b*4096+s)*16 + dgrp
    int q  = idx >> 4;
    int dg = idx & 15;
    fx4 s = (fx4){0.f, 0.f, 0.f, 0.f};
    float l = 0.f;
    #pragma unroll
    for (int c = 0; c < 8; c++) {
        u16x4 h = *(const u16x4*)(pOb + ((size_t)c * 16384 + q) * 64 + dg * 4);
        s.x += bf2f(h.x);
        s.y += bf2f(h.y);
        s.z += bf2f(h.z);
        s.w += bf2f(h.w);
        l += pL[(size_t)c * 16384 + q];
    }
    float scale = mask[q] / l;
    *(fx4*)(out + (size_t)q * 64 + dg * 4) = s * scale;
}

// ---------------------------------------------------------------------------
extern "C" void kernel_launch(void* const* d_in, const int* in_sizes, int n_in,
                              void* d_out, int out_size, void* d_ws, size_t ws_size,
                              hipStream_t stream)
{
    const float* X    = (const float*)d_in[0];
    const float* mask = (const float*)d_in[1];
    const float* Wq   = (const float*)d_in[2];
    const float* bq   = (const float*)d_in[3];
    const float* Wk   = (const float*)d_in[4];
    const float* bk   = (const float*)d_in[5];
    const float* Wv   = (const float*)d_in[6];
    const float* bv   = (const float*)d_in[7];
    float* out = (float*)d_out;

    char* ws = (char*)d_ws;
    unsigned short* q_hi  = (unsigned short*)(ws);                       // 2 MB
    unsigned short* q_lo  = (unsigned short*)(ws + (size_t)(2u << 20));  // 2 MB
    unsigned short* k_bf  = (unsigned short*)(ws + (size_t)(4u << 20));  // 2 MB
    unsigned short* vt_g  = (unsigned short*)(ws + (size_t)(6u << 20));  // 2 MB  [b][d][s]
    unsigned short* wt_hi = (unsigned short*)(ws + (size_t)(8u << 20));  // 384 KB
    unsigned short* wt_lo = (unsigned short*)(ws + (size_t)(8u << 20) + 393216);
    unsigned short* pOb   = (unsigned short*)(ws + (size_t)(9u << 20));  // 16 MB [8][16384][64] bf16
    float*          pL    = (float*)(ws + (size_t)(25u << 20));          // 512 KB [8][16384]

    hipLaunchKernelGGL(prep_w_kernel, dim3(3, 16), dim3(256), 0, stream,
                       Wq, Wk, Wv, wt_hi, wt_lo);
    hipLaunchKernelGGL(proj_kernel, dim3(768), dim3(256), 0, stream,
                       X, wt_hi, wt_lo, bq, bk, bv, q_hi, q_lo, k_bf, vt_g);
    hipLaunchKernelGGL(attn_kernel, dim3(64, 8, 4), dim3(256), 0, stream,
                       q_hi, q_lo, k_bf, vt_g, pOb, pL);
    hipLaunchKernelGGL(combine_kernel, dim3(1024), dim3(256), 0, stream,
                       pOb, pL, mask, out);
}

// Round 8
// 177.664 us; speedup vs baseline: 1.0142x; 1.0142x over previous
//
#include <hip/hip_runtime.h>

// B=4, S=4096, D_IN=1024, D_QK=D_V=64
// out = softmax(relu(XWq+bq) @ relu(XWk+bk)^T) @ relu(XWv+bv) * mask

typedef short s16x8 __attribute__((ext_vector_type(8)));      // 8x16b (4 VGPRs) MFMA frag
typedef _Float16 f16x8 __attribute__((ext_vector_type(8)));   // 8 fp16 (4 VGPRs)
typedef float fx4   __attribute__((ext_vector_type(4)));      // MFMA accum frag
typedef unsigned short u16x4 __attribute__((ext_vector_type(4)));

#define LOG2E 1.4426950408889634f

__device__ __forceinline__ unsigned short f2bf(float x) {   // fp32 -> bf16 RTN
    unsigned int u = __float_as_uint(x);
    u += 0x7FFFu + ((u >> 16) & 1u);
    return (unsigned short)(u >> 16);
}
__device__ __forceinline__ float bf2f(unsigned short b) {
    return __uint_as_float(((unsigned int)b) << 16);
}

// ---------------------------------------------------------------------------
// Kernel 1: transpose W{q,k,v} [1024][64] fp32 into W^T fp16 [3][64][1024].
// fp16 (11-bit mantissa) needs no hi/lo split for this GEMM: proj error
// ~1e-4, far below the bf16 rounding already applied to q/k/v outputs.
// ---------------------------------------------------------------------------
__global__ __launch_bounds__(256) void prep_w_kernel(
    const float* __restrict__ Wq, const float* __restrict__ Wk, const float* __restrict__ Wv,
    _Float16* __restrict__ wt_h)
{
    __shared__ __align__(16) _Float16 sh[64][72];   // [c][k_local]

    const int y  = blockIdx.x;
    const int kt = blockIdx.y;
    const float* W = (y == 0) ? Wq : (y == 1) ? Wk : Wv;
    const int t  = threadIdx.x;

    const int kl = t >> 2;
    const int c0 = (t & 3) * 16;
    const float* src = W + (size_t)(kt * 64 + kl) * 64 + c0;
    #pragma unroll
    for (int j = 0; j < 4; j++) {
        fx4 v = *(const fx4*)(src + j * 4);
        #pragma unroll
        for (int i = 0; i < 4; i++)
            sh[c0 + j * 4 + i][kl] = (_Float16)v[i];
    }
    __syncthreads();

    const int c  = t >> 2;
    const int k0 = (t & 3) * 16;
    size_t o = (size_t)(y * 64 + c) * 1024 + kt * 64 + k0;
    *(f16x8*)(wt_h + o)     = *(const f16x8*)&sh[c][k0];
    *(f16x8*)(wt_h + o + 8) = *(const f16x8*)&sh[c][k0 + 8];
}

// ---------------------------------------------------------------------------
// Kernel 2: projection v4 — fp16 MFMA, NO compensation (3x less MFMA+VALU
// than the bf16 hi/lo version). X streamed global->VGPR in A-fragment layout
// (32 B/lane contiguous), converted to fp16 in-register. W^T fp16 staged in
// LDS in K-chunks of 256 (33.8 KB, 8 barriers total) with register prefetch.
// XCD swizzle keeps the 3 y-blocks of an m-tile on one XCD (L2 X reuse).
// y==0 -> q hi/lo bf16; y==1 -> k bf16; y==2 -> V^T [b][d][s] bf16.
// ---------------------------------------------------------------------------
__global__ __launch_bounds__(256, 4) void proj_kernel(
    const float* __restrict__ X,
    const _Float16* __restrict__ wt_h,
    const float* __restrict__ bq, const float* __restrict__ bk, const float* __restrict__ bv,
    unsigned short* __restrict__ q_hi, unsigned short* __restrict__ q_lo,
    unsigned short* __restrict__ k_bf, unsigned short* __restrict__ vt_g)
{
    __shared__ __align__(16) _Float16 wls[64][264];  // [col][k0..255, +8 pad]

    const int tid  = threadIdx.x;
    const int lane = tid & 63;
    const int w    = tid >> 6;      // 0..3 (16-row strip per wave)
    const int quad = lane >> 4;
    const int l15  = lane & 15;

    // XCD swizzle decode: f = (mt & 7) + 8*(y + 3*(mt >> 3))
    const int f   = blockIdx.x;
    const int xcd = f & 7;
    const int jj  = f >> 3;
    const int y   = jj % 3;         // 0=q 1=k 2=v
    const int m0  = ((jj / 3) * 8 + xcd) * 64;

    const int row = m0 + w * 16 + l15;
    const float* xbase = X + (size_t)row * 1024;

    // W chunk staging: 64 cols x 256 k per chunk; thread stages 64 shorts
    const int wcol = tid >> 2;            // 0..63
    const int wk0  = (tid & 3) * 64;      // 0/64/128/192
    const size_t wgb = (size_t)(y * 64 + wcol) * 1024 + wk0;

    // prefetch W chunk 0 (8x f16x8 = 32 VGPRs)
    f16x8 wr[8];
    #pragma unroll
    for (int i = 0; i < 8; i++)
        wr[i] = *(const f16x8*)(wt_h + wgb + i * 8);

    // prefetch X for kc=0 (A-fragment layout, 2 ks x 32 B)
    fx4 xc[2][2];
    #pragma unroll
    for (int ks = 0; ks < 2; ks++) {
        xc[ks][0] = *(const fx4*)(xbase + ks * 32 + quad * 8);
        xc[ks][1] = *(const fx4*)(xbase + ks * 32 + quad * 8 + 4);
    }

    fx4 acc[4];
    #pragma unroll
    for (int nt = 0; nt < 4; nt++) acc[nt] = (fx4){0.f, 0.f, 0.f, 0.f};

    for (int ch = 0; ch < 4; ch++) {      // 4 chunks x 256 K
        if (ch) __syncthreads();          // prev chunk's LDS readers done
        #pragma unroll
        for (int i = 0; i < 8; i++)
            *(f16x8*)&wls[wcol][wk0 + i * 8] = wr[i];
        __syncthreads();
        if (ch < 3) {                     // prefetch next W chunk (L2-hit)
            #pragma unroll
            for (int i = 0; i < 8; i++)
                wr[i] = *(const f16x8*)(wt_h + wgb + (ch + 1) * 256 + i * 8);
        }

        #pragma unroll
        for (int kk = 0; kk < 4; kk++) {
            const int kc = ch * 4 + kk;
            // prefetch next kc's X while computing this one
            fx4 xn[2][2];
            if (kc < 15) {
                #pragma unroll
                for (int ks = 0; ks < 2; ks++) {
                    xn[ks][0] = *(const fx4*)(xbase + (kc + 1) * 64 + ks * 32 + quad * 8);
                    xn[ks][1] = *(const fx4*)(xbase + (kc + 1) * 64 + ks * 32 + quad * 8 + 4);
                }
            }
            // convert X regs -> fp16 A-fragments
            f16x8 ah[2];
            #pragma unroll
            for (int ks = 0; ks < 2; ks++)
                #pragma unroll
                for (int j = 0; j < 2; j++) {
                    fx4 v = xc[ks][j];
                    #pragma unroll
                    for (int i = 0; i < 4; i++)
                        ah[ks][j * 4 + i] = (_Float16)v[i];
                }
            // MFMA against W fragments from LDS (single fp16, no comp)
            #pragma unroll
            for (int nt = 0; nt < 4; nt++) {
                #pragma unroll
                for (int ks = 0; ks < 2; ks++) {
                    const int ko = kk * 64 + ks * 32 + quad * 8;
                    f16x8 bh = *(const f16x8*)&wls[nt * 16 + l15][ko];
                    acc[nt] = __builtin_amdgcn_mfma_f32_16x16x32_f16(ah[ks], bh, acc[nt], 0, 0, 0);
                }
            }
            #pragma unroll
            for (int ks = 0; ks < 2; ks++) {
                xc[ks][0] = xn[ks][0];
                xc[ks][1] = xn[ks][1];
            }
        }
    }
    __syncthreads();   // all LDS reads done before vtr alias writes

    // epilogue: bias + relu, write per-matrix
    const float* bias = (y == 0) ? bq : (y == 1) ? bk : bv;
    const int b   = m0 >> 12;
    const int s0b = m0 & 4095;
    unsigned short* vtr = (unsigned short*)&wls[0][0];  // alias: [64 d][72]

    #pragma unroll
    for (int nt = 0; nt < 4; nt++) {
        int col = nt * 16 + l15;
        float bb = bias[col];
        int rloc = w * 16 + quad * 4;   // local row 0..63
        #pragma unroll
        for (int r = 0; r < 4; r++) {
            float v = acc[nt][r] + bb;
            v = fmaxf(v, 0.f);
            size_t grow = (size_t)(m0 + rloc + r);
            if (y == 0) {
                unsigned short h = f2bf(v);
                unsigned short l = f2bf(v - bf2f(h));
                q_hi[grow * 64 + col] = h;
                q_lo[grow * 64 + col] = l;
            } else if (y == 1) {
                k_bf[grow * 64 + col] = f2bf(v);
            } else {
                vtr[col * 72 + rloc + r] = f2bf(v);  // transpose via LDS
            }
        }
    }
    if (y == 2) {
        __syncthreads();
        int rowd = tid >> 2;          // d 0..63
        int off  = (tid & 3) * 16;    // s chunk (16 el = 32 B)
        s16x8 v0 = *(const s16x8*)&vtr[rowd * 72 + off];
        s16x8 v1 = *(const s16x8*)&vtr[rowd * 72 + off + 8];
        *(s16x8*)(vt_g + (size_t)(b * 64 + rowd) * 4096 + s0b + off)     = v0;
        *(s16x8*)(vt_g + (size_t)(b * 64 + rowd) * 4096 + s0b + off + 8) = v1;
    }
}

// ---------------------------------------------------------------------------
// Kernel 3: fused attention, KV-split. grid (64 qtiles, 8 chunks, 4 batch) =
// 2048 blocks. Block = 64 q-rows, 4 waves, 8 KV tiles each. LDS 23.5 KB ->
// 6 blocks/CU. NEW: next KV tile is register-prefetched during compute, so
// global-load latency is hidden instead of exposed inside the barrier pair.
// Writes UNNORMALIZED partial O (bf16) and row-sum l (fp32).
// No online max: q,k >= 0 post-relu => exp safe in fp32.
// ---------------------------------------------------------------------------
__global__ __launch_bounds__(256, 6) void attn_kernel(
    const unsigned short* __restrict__ q_hi, const unsigned short* __restrict__ q_lo,
    const unsigned short* __restrict__ k_bf, const unsigned short* __restrict__ vt_g,
    unsigned short* __restrict__ pOb, float* __restrict__ pL)
{
    __shared__ __align__(16) unsigned short kt[64][72];      // [key][dim]
    __shared__ __align__(16) unsigned short vt[64][72];      // [dim][key]  (V^T)
    __shared__ __align__(16) unsigned short pt[4][16][40];   // per-wave P [q][key half]

    const int tid  = threadIdx.x;
    const int lane = tid & 63;
    const int w    = tid >> 6;
    const int quad = lane >> 4;
    const int l15  = lane & 15;
    const int ck   = blockIdx.y;         // key chunk (512 keys)
    const int b    = blockIdx.z;
    const int q0   = blockIdx.x * 64;    // within batch

    // Q fragments (A layout: m=lane&15, k=quad*8+j), split hi/lo
    const size_t qoff = ((size_t)b * 4096 + q0 + w * 16 + l15) * 64 + quad * 8;
    s16x8 qh0 = *(const s16x8*)(q_hi + qoff);
    s16x8 qh1 = *(const s16x8*)(q_hi + qoff + 32);
    s16x8 ql0 = *(const s16x8*)(q_lo + qoff);
    s16x8 ql1 = *(const s16x8*)(q_lo + qoff + 32);

    fx4 accO[4];
    #pragma unroll
    for (int nt = 0; nt < 4; nt++) accO[nt] = (fx4){0.f, 0.f, 0.f, 0.f};
    float lsum[4] = {0.f, 0.f, 0.f, 0.f};

    const unsigned short* kgb = k_bf + (size_t)b * 4096 * 64;  // [s][64]
    const unsigned short* vgb = vt_g + (size_t)b * 64 * 4096;  // [d][s]

    const int srow = tid >> 3;        // 0..31
    const int soff = (tid & 7) * 8;

    // prefetch KV tile 0 into registers
    s16x8 kr[2], vr[2];
    {
        const unsigned short* kg = kgb + (size_t)(ck * 8) * 4096;
        #pragma unroll
        for (int i = 0; i < 2; i++) {
            int row = srow + i * 32;
            kr[i] = *(const s16x8*)(kg + (size_t)row * 64 + soff);
            vr[i] = *(const s16x8*)(vgb + (size_t)row * 4096 + (ck * 8) * 64 + soff);
        }
    }

    for (int i2 = 0; i2 < 8; i2++) {
        const int it = ck * 8 + i2;
        if (i2) __syncthreads();         // prev iter's LDS readers done
        #pragma unroll
        for (int i = 0; i < 2; i++) {
            int row = srow + i * 32;
            *(s16x8*)&kt[row][soff] = kr[i];
            *(s16x8*)&vt[row][soff] = vr[i];
        }
        __syncthreads();
        if (i2 < 7) {                    // prefetch next tile during compute
            const unsigned short* kg = kgb + (size_t)(it + 1) * 4096;
            #pragma unroll
            for (int i = 0; i < 2; i++) {
                int row = srow + i * 32;
                kr[i] = *(const s16x8*)(kg + (size_t)row * 64 + soff);
                vr[i] = *(const s16x8*)(vgb + (size_t)row * 4096 + (it + 1) * 64 + soff);
            }
        }

        #pragma unroll
        for (int kh = 0; kh < 2; kh++) {
            // S = Q K^T for 32-key half (hi/lo compensated)
            #pragma unroll
            for (int nt2 = 0; nt2 < 2; nt2++) {
                int key = kh * 32 + nt2 * 16 + l15;
                s16x8 k0 = *(const s16x8*)&kt[key][quad * 8];
                s16x8 k1 = *(const s16x8*)&kt[key][32 + quad * 8];
                fx4 sc = (fx4){0.f, 0.f, 0.f, 0.f};
                sc = __builtin_amdgcn_mfma_f32_16x16x32_bf16(qh0, k0, sc, 0, 0, 0);
                sc = __builtin_amdgcn_mfma_f32_16x16x32_bf16(ql0, k0, sc, 0, 0, 0);
                sc = __builtin_amdgcn_mfma_f32_16x16x32_bf16(qh1, k1, sc, 0, 0, 0);
                sc = __builtin_amdgcn_mfma_f32_16x16x32_bf16(ql1, k1, sc, 0, 0, 0);
                // P = exp(S) -> bf16 -> wave-private LDS (C -> A layout)
                #pragma unroll
                for (int r = 0; r < 4; r++) {
                    float p = __builtin_amdgcn_exp2f(sc[r] * LOG2E);
                    unsigned short pb = f2bf(p);
                    lsum[r] += bf2f(pb);   // denominator matches rounded numerator
                    pt[w][quad * 4 + r][nt2 * 16 + l15] = pb;
                }
            }
            // O += P_half V_half  (k=32 exactly fills one MFMA)
            s16x8 pa = *(const s16x8*)&pt[w][l15][quad * 8];
            #pragma unroll
            for (int nt = 0; nt < 4; nt++) {
                s16x8 vf = *(const s16x8*)&vt[nt * 16 + l15][kh * 32 + quad * 8];
                accO[nt] = __builtin_amdgcn_mfma_f32_16x16x32_bf16(pa, vf, accO[nt], 0, 0, 0);
            }
        }
    }

    // reduce row-sums across the 16 lanes sharing each row group
    #pragma unroll
    for (int r = 0; r < 4; r++) {
        float v = lsum[r];
        #pragma unroll
        for (int o = 1; o < 16; o <<= 1) v += __shfl_xor(v, o);
        lsum[r] = v;
    }
    // write partials: pOb[ck][b*4096+q][64] (bf16), pL[ck][b*4096+q] (fp32)
    #pragma unroll
    for (int r = 0; r < 4; r++) {
        int qrow = q0 + w * 16 + quad * 4 + r;
        size_t grow = (size_t)b * 4096 + qrow;
        #pragma unroll
        for (int nt = 0; nt < 4; nt++)
            pOb[((size_t)ck * 16384 + grow) * 64 + nt * 16 + l15] = f2bf(accO[nt][r]);
        if (l15 == 0)
            pL[(size_t)ck * 16384 + grow] = lsum[r];
    }
}

// ---------------------------------------------------------------------------
// Kernel 4: combine partials: out = (sum_c pOb) * mask / (sum_c pL)
// ---------------------------------------------------------------------------
__global__ __launch_bounds__(256) void combine_kernel(
    const unsigned short* __restrict__ pOb, const float* __restrict__ pL,
    const float* __restrict__ mask, float* __restrict__ out)
{
    int idx = blockIdx.x * 256 + threadIdx.x;   // 262144 = (b*4096+s)*16 + dgrp
    int q  = idx >> 4;
    int dg = idx & 15;
    fx4 s = (fx4){0.f, 0.f, 0.f, 0.f};
    float l = 0.f;
    #pragma unroll
    for (int c = 0; c < 8; c++) {
        u16x4 h = *(const u16x4*)(pOb + ((size_t)c * 16384 + q) * 64 + dg * 4);
        s.x += bf2f(h.x);
        s.y += bf2f(h.y);
        s.z += bf2f(h.z);
        s.w += bf2f(h.w);
        l += pL[(size_t)c * 16384 + q];
    }
    float scale = mask[q] / l;
    *(fx4*)(out + (size_t)q * 64 + dg * 4) = s * scale;
}

// ---------------------------------------------------------------------------
extern "C" void kernel_launch(void* const* d_in, const int* in_sizes, int n_in,
                              void* d_out, int out_size, void* d_ws, size_t ws_size,
                              hipStream_t stream)
{
    const float* X    = (const float*)d_in[0];
    const float* mask = (const float*)d_in[1];
    const float* Wq   = (const float*)d_in[2];
    const float* bq   = (const float*)d_in[3];
    const float* Wk   = (const float*)d_in[4];
    const float* bk   = (const float*)d_in[5];
    const float* Wv   = (const float*)d_in[6];
    const float* bv   = (const float*)d_in[7];
    float* out = (float*)d_out;

    char* ws = (char*)d_ws;
    unsigned short* q_hi  = (unsigned short*)(ws);                       // 2 MB
    unsigned short* q_lo  = (unsigned short*)(ws + (size_t)(2u << 20));  // 2 MB
    unsigned short* k_bf  = (unsigned short*)(ws + (size_t)(4u << 20));  // 2 MB
    unsigned short* vt_g  = (unsigned short*)(ws + (size_t)(6u << 20));  // 2 MB  [b][d][s]
    _Float16*       wt_h  = (_Float16*)(ws + (size_t)(8u << 20));        // 384 KB fp16 W^T
    unsigned short* pOb   = (unsigned short*)(ws + (size_t)(9u << 20));  // 16 MB [8][16384][64] bf16
    float*          pL    = (float*)(ws + (size_t)(25u << 20));          // 512 KB [8][16384]

    hipLaunchKernelGGL(prep_w_kernel, dim3(3, 16), dim3(256), 0, stream,
                       Wq, Wk, Wv, wt_h);
    hipLaunchKernelGGL(proj_kernel, dim3(768), dim3(256), 0, stream,
                       X, wt_h, bq, bk, bv, q_hi, q_lo, k_bf, vt_g);
    hipLaunchKernelGGL(attn_kernel, dim3(64, 8, 4), dim3(256), 0, stream,
                       q_hi, q_lo, k_bf, vt_g, pOb, pL);
    hipLaunchKernelGGL(combine_kernel, dim3(1024), dim3(256), 0, stream,
                       pOb, pL, mask, out);
}